// Round 2
// baseline (252.305 us; speedup 1.0000x reference)
//
#include <hip/hip_runtime.h>
#include <hip/hip_bf16.h>

#define KK 128
#define VV 50000
#define DD 8192
#define NN 512
#define TPB 128          // threads per block (1 doc per block)
#define TPT 4            // tokens per thread

// EPS = 0.01 * 100^(-0.55)
#define EPS_F      0.0007943282347242814f
#define EPS_HALF_F 0.0003971641173621407f

// output layout (flat float32, in return order)
#define OFF_ETA 0
#define OFF_Z2  ((size_t)DD * KK)                    // 1048576
#define OFF_CDK (OFF_Z2 + (size_t)DD * NN)           // 5242880
#define OFF_CWK (OFF_CDK + (size_t)DD * KK)          // 6291456
#define OFF_CK  (OFF_CWK + (size_t)VV * KK)          // 12691456

typedef int   i4 __attribute__((ext_vector_type(4)));
typedef float f4 __attribute__((ext_vector_type(4)));

__global__ __launch_bounds__(TPB) void dtm_main(
    const int* __restrict__ word_ids, const int* __restrict__ z,
    const float* __restrict__ eta, const float* __restrict__ alpha,
    const float* __restrict__ phi, const int* __restrict__ prop_word,
    const int* __restrict__ prop_topic, const float* __restrict__ u_word,
    const float* __restrict__ u_topic, const float* __restrict__ xi,
    float* __restrict__ out)
{
    const int d = blockIdx.x;
    const int tid = threadIdx.x;

    __shared__ int   cnt0[KK];
    __shared__ int   cnt2[KK];
    __shared__ float etan[KK];
    __shared__ float wmax[2];
    __shared__ float wsum[2];

    cnt0[tid] = 0;
    cnt2[tid] = 0;
    __syncthreads();

    const int tb = d * NN + tid * TPT;

    // streaming token loads — nontemporal to keep phi/CWK resident in L2
    i4 zz  = __builtin_nontemporal_load((const i4*)(z + tb));
    i4 ww  = __builtin_nontemporal_load((const i4*)(word_ids + tb));
    i4 pp1 = __builtin_nontemporal_load((const i4*)(prop_word + tb));
    i4 pp2 = __builtin_nontemporal_load((const i4*)(prop_topic + tb));
    f4 uw  = __builtin_nontemporal_load((const f4*)(u_word + tb));
    f4 ut  = __builtin_nontemporal_load((const f4*)(u_topic + tb));

    atomicAdd(&cnt0[zz.x], 1);
    atomicAdd(&cnt0[zz.y], 1);
    atomicAdd(&cnt0[zz.z], 1);
    atomicAdd(&cnt0[zz.w], 1);

    // ---- softmax over eta[d,:] (128 threads, 2 waves) ----
    float e = __builtin_nontemporal_load(&eta[(size_t)d * KK + tid]);
    float m = e;
    #pragma unroll
    for (int o = 32; o > 0; o >>= 1) m = fmaxf(m, __shfl_xor(m, o));
    if ((tid & 63) == 0) wmax[tid >> 6] = m;
    __syncthreads();                       // also fences cnt0 histogram
    m = fmaxf(wmax[0], wmax[1]);
    float ex = __expf(e - m);
    float s = ex;
    #pragma unroll
    for (int o = 32; o > 0; o >>= 1) s += __shfl_xor(s, o);
    if ((tid & 63) == 0) wsum[tid >> 6] = s;
    __syncthreads();
    s = wsum[0] + wsum[1];

    // ---- SGLD eta update ----
    {
        float sm    = ex / s;
        float grad  = (float)cnt0[tid] - (float)NN * sm;
        float prior = alpha[tid] - e;                     // ETA_VAR = 1
        float en = e + EPS_HALF_F * (grad + prior) + xi[d] * EPS_F;
        etan[tid] = en;
        __builtin_nontemporal_store(en, &out[OFF_ETA + (size_t)d * KK + tid]);
    }
    __syncthreads();

    // ---- MH steps, phase-batched over 4 tokens ----
    int   wa[TPT]  = {ww.x,  ww.y,  ww.z,  ww.w};
    int   za[TPT]  = {zz.x,  zz.y,  zz.z,  zz.w};
    int   p1a[TPT] = {pp1.x, pp1.y, pp1.z, pp1.w};
    int   p2a[TPT] = {pp2.x, pp2.y, pp2.z, pp2.w};
    float uwa[TPT] = {uw.x,  uw.y,  uw.z,  uw.w};
    float uta[TPT] = {ut.x,  ut.y,  ut.z,  ut.w};

    float gp[TPT], gz[TPT];
    #pragma unroll
    for (int i = 0; i < TPT; ++i) {
        const float* r = phi + (size_t)wa[i] * KK;
        gp[i] = r[p1a[i]];
        gz[i] = r[za[i]];
    }

    int z2a[TPT];
    #pragma unroll
    for (int i = 0; i < TPT; ++i) {
        // clips/floors in jax_exp never bind for |x|<~12; ratio == exp(diff)
        float a1 = __expf(gp[i] - gz[i]);
        int z1 = (uwa[i] < a1) ? p1a[i] : za[i];
        float a2 = __expf(etan[p2a[i]] - etan[z1]);
        z2a[i] = (uta[i] < a2) ? p2a[i] : z1;
    }

    f4 z2f = { (float)z2a[0], (float)z2a[1], (float)z2a[2], (float)z2a[3] };
    __builtin_nontemporal_store(z2f, (f4*)(out + OFF_Z2 + tb));

    float* cwk2 = out + OFF_CWK;
    #pragma unroll
    for (int i = 0; i < TPT; ++i) {
        atomicAdd(&cnt2[z2a[i]], 1);
        unsafeAtomicAdd(&cwk2[(size_t)wa[i] * KK + z2a[i]], 1.0f);
    }
    __syncthreads();

    __builtin_nontemporal_store((float)cnt2[tid],
                                &out[OFF_CDK + (size_t)d * KK + tid]);
}

// CK2[k] = sum_d CDK2[d,k]; 128 blocks x 256 threads, each block sums 64 docs
__global__ __launch_bounds__(256) void ck_reduce(const float* __restrict__ cdk2,
                                                 float* __restrict__ ck2)
{
    const int b = blockIdx.x;
    const int tid = threadIdx.x;
    const size_t base = (size_t)b * 64 * KK;   // 64 docs per block
    float part = 0.0f;
    for (int i = tid; i < 64 * KK; i += 256)   // i % 128 == tid % 128
        part += cdk2[base + i];
    __shared__ float sbuf[256];
    sbuf[tid] = part;
    __syncthreads();
    if (tid < KK)
        unsafeAtomicAdd(&ck2[tid], sbuf[tid] + sbuf[tid + KK]);
}

extern "C" void kernel_launch(void* const* d_in, const int* in_sizes, int n_in,
                              void* d_out, int out_size, void* d_ws, size_t ws_size,
                              hipStream_t stream) {
    const int*   word_ids   = (const int*)d_in[0];
    const int*   z          = (const int*)d_in[1];
    const float* eta        = (const float*)d_in[2];
    const float* alpha      = (const float*)d_in[3];
    const float* phi        = (const float*)d_in[4];
    const int*   prop_word  = (const int*)d_in[5];
    const int*   prop_topic = (const int*)d_in[6];
    const float* u_word     = (const float*)d_in[7];
    const float* u_topic    = (const float*)d_in[8];
    const float* xi         = (const float*)d_in[9];
    float* out = (float*)d_out;

    // zero CWK2 + CK2 (atomically accumulated into)
    hipMemsetAsync(out + OFF_CWK, 0, ((size_t)VV * KK + KK) * sizeof(float), stream);

    dtm_main<<<DD, TPB, 0, stream>>>(word_ids, z, eta, alpha, phi,
                                     prop_word, prop_topic, u_word, u_topic, xi, out);

    ck_reduce<<<KK, 256, 0, stream>>>(out + OFF_CDK, out + OFF_CK);
}